// Round 5
// baseline (1286.009 us; speedup 1.0000x reference)
//
#include <hip/hip_runtime.h>
#include <hip/hip_bf16.h>
#include <cstddef>

// Problem constants
#define BB    32
#define IMG   224
#define CIN   3
#define ED    64
#define TD    64
#define MM    32
#define HP    56
#define TT    3136      // 56*56
#define C4    256       // 4*ED
#define KQVN  192       // 3*TD

typedef __attribute__((ext_vector_type(8))) short bf16x8;
typedef __attribute__((ext_vector_type(4))) float f32x4;

// workspace offsets (float units). Temporal plan:
//  step1 wtrans -> weights (aliased in PART region, dead after kqv)
//  step2 conv1 -> c1b  [19.27M,32.11M)
//  step3 conv2 -> c2b  [6.42M,9.63M)      (reads c1b)
//  step4 conv3 -> convX[0,6.42M)          (reads c2b)
//  step5 prm_ln -> xn  [6.42M,19.27M)     (c1b? no: c2b dead; xn overwrites c2b zone)
//  step6 kqv   -> v[19.27M,25.69M) kp[25.69M,28.9M) qp[28.9M,32.11M)  (c1b dead, overwritten)
//  step7+ kpsum/kptv -> part[32.11M,33.16M) (weights dead, overwritten) kptv,kpsum
#define OFF_CONVX  0u           // 6,422,528 f
#define OFF_XN     6422528u     // 12,845,056 f (25,690,112 bf16)
#define OFF_C2B    6422528u     // 3,211,264 f (bf16) — aliases xn head; dead before xn written
#define OFF_C1B    19267584u    // 12,845,056 f (bf16) — dead before v/kp/qp written
#define OFF_V      19267584u    // 6,422,528 f
#define OFF_KP     25690112u    // 3,211,264 f
#define OFF_QP     28901376u    // 3,211,264 f
#define OFF_PART   32112640u    // 1,048,576 f
#define OFF_KPTV   33161216u    // 65,536 f
#define OFF_KPSUM  33226752u    // 1,024 f
// weights aliased into PART region (dead once k_kptv writes part at step 8)
#define OFF_WPT    (OFF_PART)             // 37,632 f
#define OFF_WKB    (OFF_PART + 37632u)    // 24,576 f (49,152 bf16)
#define OFF_WC2B   (OFF_PART + 62208u)    // 18,432 f (36,864 bf16)
#define OFF_WT3B   (OFF_PART + 80640u)    // 18,432 f (36,864 bf16)  ends 32,211,712 < OFF_KPTV
// total 33,227,776 f = 132.9 MB (same as R1 footprint, known to fit)

__device__ __forceinline__ float geluf(float v){
  return 0.5f*v*(1.f + erff(v*0.70710678118654752f));
}
__device__ __forceinline__ float siluf(float v){
  return v/(1.f + expf(-v));
}
__device__ __forceinline__ ushort bfbits(float v){
  __hip_bfloat16 h = __float2bfloat16(v);
  return *reinterpret_cast<ushort*>(&h);
}

// ---------------- weight transposes / casts
__global__ __launch_bounds__(256) void k_wtrans(
    const float* __restrict__ prm_w, const float* __restrict__ kqv_w,
    const float* __restrict__ pcm_w2, const float* __restrict__ pcm_w3,
    float* __restrict__ wpt, __hip_bfloat16* __restrict__ wkb,
    __hip_bfloat16* __restrict__ wc2b, __hip_bfloat16* __restrict__ wt3b)
{
  int idx = blockIdx.x*256 + threadIdx.x;
  if (idx < 37632){
    int oc = idx & 63, r = idx >> 6;        // r = i*147+tap
    int i = r/147, tap = r - i*147;
    wpt[idx] = prm_w[(i*64 + oc)*147 + tap];
  } else if (idx < 86784){
    int i4 = idx - 37632;                   // [j][c] row-major straight cast
    wkb[i4] = __float2bfloat16(kqv_w[i4]);
  } else if (idx < 123648){
    int i2 = idx - 86784;                   // wc2b[oc][ (kh*3+kw)*64+ci ]
    int oc = i2/576, rem = i2 - oc*576;
    int khkw = rem >> 6, ci = rem & 63;
    int kh = khkw/3, kw = khkw - kh*3;
    wc2b[i2] = __float2bfloat16(pcm_w2[(oc*64+ci)*9 + kh*3 + kw]);
  } else if (idx < 160512){
    int i3 = idx - 123648;
    int oc = i3/576, rem = i3 - oc*576;
    int khkw = rem >> 6, ci = rem & 63;
    int kh = khkw/3, kw = khkw - kh*3;
    wt3b[i3] = __float2bfloat16(pcm_w3[(oc*64+ci)*9 + kh*3 + kw]);
  }
}

// ---------------- conv1: x(32,3,224,224) -> c1b NHWC bf16 (32,112,112,64), 3x3 s2 p1, SiLU
__global__ __launch_bounds__(256) void k_conv1(
    const float* __restrict__ x, const float* __restrict__ w,
    const float* __restrict__ bias, __hip_bfloat16* __restrict__ c1b)
{
  __shared__ __align__(16) float xs[3][5][226];
  __shared__ float ws1[1728];
  __shared__ float bs[64];
  const int t = threadIdx.x;
  const int b = blockIdx.y;
  const int oh0 = blockIdx.x*2;
  const int ih0 = oh0*2 - 1;
  const float* xb = x + (size_t)b*CIN*IMG*IMG;
  for (int idx = t; idx < 3390; idx += 256){
    int ci = idx/1130, rem = idx - ci*1130;
    int r = rem/226, c = rem - r*226;
    int ih = ih0 + r, iw = c - 1;
    float v = 0.f;
    if ((unsigned)ih < (unsigned)IMG && (unsigned)iw < (unsigned)IMG)
      v = xb[(ci*IMG+ih)*IMG+iw];
    xs[ci][r][c] = v;
  }
  for (int idx = t; idx < 1728; idx += 256) ws1[idx] = w[idx];
  if (t < 64) bs[t] = bias[t];
  __syncthreads();
  if (t < 224){
    const int orow = t/112, ow = t - orow*112;
    const int rb = orow*2, cb = ow*2;
    float xr[3][3][3];
    #pragma unroll
    for (int ci=0;ci<3;++ci)
      #pragma unroll
      for (int kh=0;kh<3;++kh)
        #pragma unroll
        for (int kw=0;kw<3;++kw)
          xr[ci][kh][kw] = xs[ci][rb+kh][cb+kw];
    const int oh = oh0 + orow;
    __hip_bfloat16* dst = c1b + (((size_t)b*112+oh)*112+ow)*64;
    for (int og=0; og<8; ++og){
      ushort h8[8];
      #pragma unroll
      for (int u=0;u<8;++u){
        const int oc = og*8+u;
        float acc = bs[oc];
        const float* wp = &ws1[oc*27];
        #pragma unroll
        for (int ci=0;ci<3;++ci)
          #pragma unroll
          for (int kh=0;kh<3;++kh)
            #pragma unroll
            for (int kw=0;kw<3;++kw)
              acc += wp[(ci*3+kh)*3+kw]*xr[ci][kh][kw];
        h8[u] = bfbits(siluf(acc));
      }
      *(uint4*)(dst + og*8) = *(const uint4*)h8;
    }
  }
}

// ---------------- conv2 (MFMA implicit GEMM): c1b -> c2b NHWC bf16, 3x3 s2 p1, BN+SiLU
__global__ __launch_bounds__(256) void k_conv2(
    const __hip_bfloat16* __restrict__ c1b, const __hip_bfloat16* __restrict__ wc2b,
    const float* __restrict__ bias, const float* __restrict__ g,
    const float* __restrict__ bb, const float* __restrict__ mean,
    const float* __restrict__ var, __hip_bfloat16* __restrict__ c2b)
{
  __shared__ __align__(16) ushort xs[17*17*72];
  const int b = blockIdx.y;
  const int th = blockIdx.x/7, tw = blockIdx.x - th*7;
  const int oh0 = th*8, ow0 = tw*8;
  const int t = threadIdx.x;
  const int w = t>>6, lane = t&63, l15 = lane&15, hi = lane>>4;

  const int ih0 = oh0*2-1, iw0 = ow0*2-1;
  const ushort* c1u = (const ushort*)c1b;
  for (int seg = t; seg < 2312; seg += 256){
    int pos = seg >> 3, s8 = seg & 7;
    int r = pos/17, c = pos - r*17;
    int ih = ih0 + r, iw = iw0 + c;
    uint4 val = {0,0,0,0};
    if ((unsigned)ih < 112u && (unsigned)iw < 112u)
      val = *(const uint4*)&c1u[(((size_t)b*112+ih)*112+iw)*64 + s8*8];
    *(uint4*)&xs[(r*17+c)*72 + s8*8] = val;
  }
  __syncthreads();

  float bs4[4], iv4[4], mn4[4], bo4[4];
  #pragma unroll
  for (int nb=0;nb<4;++nb){
    int oc = nb*16+l15;
    bs4[nb] = bias[oc];
    iv4[nb] = g[oc]*rsqrtf(var[oc]+1e-5f);
    mn4[nb] = mean[oc];
    bo4[nb] = bb[oc];
  }

  f32x4 acc[4];
  #pragma unroll
  for (int nb=0;nb<4;++nb) acc[nb] = (f32x4){0.f,0.f,0.f,0.f};

  const int p = w*16 + l15, pr = p>>3, pc = p&7;
  const ushort* wq = (const ushort*)wc2b;

  for (int ks=0; ks<18; ++ks){
    const int k0 = ks*32 + hi*8;
    const int khkw = k0 >> 6, ci0 = k0 & 63;
    const int kh = khkw/3, kw = khkw - kh*3;
    bf16x8 a = *(const bf16x8*)&xs[((2*pr+kh)*17 + 2*pc+kw)*72 + ci0];
    #pragma unroll
    for (int nb=0;nb<4;++nb){
      bf16x8 bv = *(const bf16x8*)&wq[(nb*16+l15)*576 + k0];
      acc[nb] = __builtin_amdgcn_mfma_f32_16x16x32_bf16(a, bv, acc[nb], 0, 0, 0);
    }
  }

  #pragma unroll
  for (int nb=0;nb<4;++nb){
    #pragma unroll
    for (int r=0;r<4;++r){
      int pp = w*16 + hi*4 + r;
      int oh = oh0 + (pp>>3), ow = ow0 + (pp&7);
      float vv = acc[nb][r] + bs4[nb];
      vv = (vv - mn4[nb])*iv4[nb] + bo4[nb];
      c2b[(((size_t)b*56+oh)*56+ow)*64 + nb*16+l15] = __float2bfloat16(siluf(vv));
    }
  }
}

// ---------------- conv3 (MFMA implicit GEMM): c2b -> convX(32,3136,64) f32 NHWC, 3x3 s1 p1, SiLU
__global__ __launch_bounds__(256) void k_conv3(
    const __hip_bfloat16* __restrict__ c2b, const __hip_bfloat16* __restrict__ wt3b,
    const float* __restrict__ bias, float* __restrict__ convX)
{
  __shared__ __align__(16) ushort xs[10*12*72];
  const int b = blockIdx.y;
  const int th = blockIdx.x/7, tw = blockIdx.x - th*7;
  const int oh0 = th*8, ow0 = tw*8;
  const int t = threadIdx.x;
  const int w = t>>6, lane = t&63, l15 = lane&15, hi = lane>>4;

  const ushort* c2u = (const ushort*)c2b;
  for (int seg = t; seg < 960; seg += 256){
    int pos = seg >> 3, s8 = seg & 7;
    int r = pos/12, c = pos - r*12;
    int ih = oh0 - 1 + r, iw = ow0 - 1 + c;
    uint4 val = {0,0,0,0};
    if ((unsigned)ih < 56u && (unsigned)iw < 56u)
      val = *(const uint4*)&c2u[(((size_t)b*56+ih)*56+iw)*64 + s8*8];
    *(uint4*)&xs[(r*12+c)*72 + s8*8] = val;
  }
  __syncthreads();

  float bs4[4];
  #pragma unroll
  for (int nb=0;nb<4;++nb) bs4[nb] = bias[nb*16+l15];

  f32x4 acc[4];
  #pragma unroll
  for (int nb=0;nb<4;++nb) acc[nb] = (f32x4){0.f,0.f,0.f,0.f};

  const int p = w*16 + l15, pr = p>>3, pc = p&7;
  const ushort* wq = (const ushort*)wt3b;

  for (int ks=0; ks<18; ++ks){
    const int k0 = ks*32 + hi*8;
    const int khkw = k0 >> 6, ci0 = k0 & 63;
    const int kh = khkw/3, kw = khkw - kh*3;
    bf16x8 a = *(const bf16x8*)&xs[((pr+kh)*12 + pc+kw)*72 + ci0];
    #pragma unroll
    for (int nb=0;nb<4;++nb){
      bf16x8 bv = *(const bf16x8*)&wq[(nb*16+l15)*576 + k0];
      acc[nb] = __builtin_amdgcn_mfma_f32_16x16x32_bf16(a, bv, acc[nb], 0, 0, 0);
    }
  }

  #pragma unroll
  for (int nb=0;nb<4;++nb){
    #pragma unroll
    for (int r=0;r<4;++r){
      int pp = w*16 + hi*4 + r;
      int oh = oh0 + (pp>>3), ow = ow0 + (pp&7);
      int s = oh*HP + ow;
      convX[((size_t)b*TT + s)*64 + nb*16+l15] = siluf(acc[nb][r] + bs4[nb]);
    }
  }
}

// ---------------- PRM conv core: per-dilation specialization, row cached in registers
template<int D>
__device__ __forceinline__ void prm_core(const float (*xt)[25][80],
    const float* __restrict__ wq, float v[14])
{
  constexpr int R0 = 12 - 3*D;
  constexpr int QLO = R0/4;
  constexpr int QHI = (R0 + 6*D + 52)/4;
  for (int ci=0; ci<3; ++ci){
    #pragma unroll
    for (int kh=0; kh<7; ++kh){
      const float* xrow = &xt[ci][R0 + kh*D][0];
      float rx[80];
      #pragma unroll
      for (int q=QLO; q<=QHI; ++q)
        *(float4*)&rx[4*q] = *(const float4*)&xrow[4*q];
      #pragma unroll
      for (int kw=0; kw<7; ++kw){
        const float wv = wq[((ci*7+kh)*7+kw)*64];
        #pragma unroll
        for (int p=0;p<14;++p)
          v[p] += wv * rx[R0 + kw*D + 4*p];
      }
    }
  }
}

// ---------------- PRM convs + GELU + LN -> xn (bf16). one block = 14-wide strip
__global__ __launch_bounds__(256) void k_prm_ln(
    const float* __restrict__ x, const float* __restrict__ wpt,
    const float* __restrict__ prm_b, const float* __restrict__ ln_g,
    const float* __restrict__ ln_b, __hip_bfloat16* __restrict__ xn)
{
  __shared__ __align__(16) float xt[3][25][80];
  __shared__ float wred[4][14][2];
  const int t = threadIdx.x;
  const int b = blockIdx.y;
  const int oh  = blockIdx.x >> 2;
  const int owt = blockIdx.x & 3;
  const int ow0 = owt*14;
  const int ih0 = oh*4 - 11;
  const int iw0 = ow0*4 - 11;

  const float* xb = x + (size_t)b*CIN*IMG*IMG;
  for (int idx = t; idx < 6000; idx += 256){
    int ci  = idx / 2000;
    int rem = idx - ci*2000;
    int r   = rem / 80;
    int cc  = rem - r*80;
    int ih = ih0 + r, iw = iw0 + cc;
    float val = 0.f;
    if ((unsigned)ih < (unsigned)IMG && (unsigned)iw < (unsigned)IMG)
      val = xb[(ci*IMG+ih)*IMG+iw];
    xt[ci][r][cc] = val;
  }
  __syncthreads();

  const int i = t >> 6, lane = t & 63;
  float v[14];
  const float bi = prm_b[i*64+lane];
  #pragma unroll
  for (int p=0;p<14;++p) v[p] = bi;
  const float* wq = wpt + (i*147)*64 + lane;   // [tap][oc] coalesced

  if      (i == 0) prm_core<1>(xt, wq, v);
  else if (i == 1) prm_core<2>(xt, wq, v);
  else if (i == 2) prm_core<3>(xt, wq, v);
  else             prm_core<4>(xt, wq, v);

  // GELU + per-wave LN partials via shuffles
  #pragma unroll
  for (int p=0;p<14;++p) v[p] = geluf(v[p]);
  #pragma unroll
  for (int p=0;p<14;++p){
    float s1 = v[p], s2 = v[p]*v[p];
    #pragma unroll
    for (int o=32;o;o>>=1){
      s1 += __shfl_xor(s1, o, 64);
      s2 += __shfl_xor(s2, o, 64);
    }
    if (lane == 0){ wred[i][p][0] = s1; wred[i][p][1] = s2; }
  }
  __syncthreads();
  const float lg = ln_g[t], lb = ln_b[t];
  const int s_base = oh*HP + ow0;
  #pragma unroll
  for (int p=0;p<14;++p){
    float S1 = wred[0][p][0]+wred[1][p][0]+wred[2][p][0]+wred[3][p][0];
    float S2 = wred[0][p][1]+wred[1][p][1]+wred[2][p][1]+wred[3][p][1];
    float mu = S1*(1.f/256.f);
    float rs = rsqrtf(S2*(1.f/256.f) - mu*mu + 1e-5f);
    float outv = (v[p]-mu)*rs*lg + lb;
    xn[((size_t)(b*TT + s_base + p))*256 + t] = __float2bfloat16(outv);
  }
}

// ---------------- KQV GEMM (bf16 MFMA) + fused Performer feature map
__global__ __launch_bounds__(256) void k_kqv_perf(
    const __hip_bfloat16* __restrict__ xn, const __hip_bfloat16* __restrict__ wkb,
    const float* __restrict__ kqv_b, const float* __restrict__ wperf,
    float* __restrict__ v_g, float* __restrict__ kp, float* __restrict__ qp)
{
  __shared__ __align__(16) char smem[36864];     // As[64][72] | Bs[192][72] bf16 ; reused as zq[64][129] f32
  __shared__ float wperf_s[32*65];
  __shared__ float kqvb_s[192];
  __shared__ float xd_s[128];
  ushort* As = (ushort*)smem;
  ushort* Bs = (ushort*)(smem + 9216);
  float*  zq = (float*)smem;

  const int t = threadIdx.x;
  const int m0 = blockIdx.x*64;
  const int w = t >> 6, lane = t & 63;
  const int l15 = lane & 15, hi = lane >> 4;

  for (int idx = t; idx < 2048; idx += 256)
    wperf_s[(idx>>6)*65 + (idx&63)] = wperf[idx];
  if (t < 192) kqvb_s[t] = kqv_b[t];

  f32x4 acc[12];
  #pragma unroll
  for (int nb=0;nb<12;++nb) acc[nb] = (f32x4){0.f,0.f,0.f,0.f};

  const ushort* xnu = (const ushort*)xn;
  const ushort* wku = (const ushort*)wkb;

  for (int kc=0; kc<4; ++kc){
    #pragma unroll
    for (int ss=0; ss<2; ++ss){
      int seg = ss*256 + t;
      int row = seg >> 3, c8 = seg & 7;
      *(uint4*)&As[row*72 + c8*8] =
        *(const uint4*)&xnu[((size_t)(m0+row))*256 + kc*64 + c8*8];
    }
    #pragma unroll
    for (int ss=0; ss<6; ++ss){
      int seg = ss*256 + t;
      int row = seg >> 3, c8 = seg & 7;
      *(uint4*)&Bs[row*72 + c8*8] =
        *(const uint4*)&wku[row*256 + kc*64 + c8*8];
    }
    __syncthreads();
    #pragma unroll
    for (int ks=0; ks<2; ++ks){
      bf16x8 a = *(const bf16x8*)&As[(16*w + l15)*72 + ks*32 + hi*8];
      #pragma unroll
      for (int nb=0;nb<12;++nb){
        bf16x8 bv = *(const bf16x8*)&Bs[(nb*16 + l15)*72 + ks*32 + hi*8];
        acc[nb] = __builtin_amdgcn_mfma_f32_16x16x32_bf16(a, bv, acc[nb], 0, 0, 0);
      }
    }
    __syncthreads();
  }

  #pragma unroll
  for (int nb=0;nb<12;++nb){
    int col = nb*16 + l15;
    float bias = kqvb_s[col];
    #pragma unroll
    for (int r=0;r<4;++r){
      int row = w*16 + hi*4 + r;
      float val = acc[nb][r] + bias;
      if (col < 128) zq[row*129 + col] = val;
      else v_g[((size_t)(m0+row))*64 + (col-128)] = val;
    }
  }
  __syncthreads();

  if (t < 128){
    int pos = t & 63, wh = t >> 6;
    float s = 0.f;
    #pragma unroll 8
    for (int c=0;c<64;++c){
      float z = zq[pos*129 + wh*64 + c];
      s += z*z;
    }
    xd_s[t] = 0.5f*s;
  }
  __syncthreads();

  const int m = t & 31;
  #pragma unroll
  for (int it=0; it<16; ++it){
    int qi = it*8 + (t>>5);
    int pos = qi & 63, wh = qi >> 6;
    const float* zr = &zq[pos*129 + wh*64];
    const float* wr = &wperf_s[m*65];
    float wtx = 0.f;
    #pragma unroll 8
    for (int c=0;c<64;++c) wtx += zr[c]*wr[c];
    float outv = expf(wtx - xd_s[qi]) * 0.17677669529663687f;
    float* dst = wh ? qp : kp;
    dst[((size_t)(m0+pos))*32 + m] = outv;
  }
}

// ---------------- kpsum[b][m] = sum_t kp[b][t][m]
__global__ __launch_bounds__(256) void k_kpsum(
    const float* __restrict__ kp, float* __restrict__ kpsum)
{
  const int b = blockIdx.x;
  const int m = threadIdx.x & 31, g = threadIdx.x >> 5;
  __shared__ float part[8][32];
  float s = 0.f;
  for (int tt = g; tt < TT; tt += 8)
    s += kp[((size_t)b*TT + tt)*MM + m];
  part[g][m] = s;
  __syncthreads();
  if (threadIdx.x < 32){
    float a = 0.f;
    #pragma unroll
    for (int g2=0;g2<8;++g2) a += part[g2][threadIdx.x];
    kpsum[b*MM + threadIdx.x] = a;
  }
}

// ---------------- kptv partials
__global__ __launch_bounds__(256) void k_kptv(
    const float* __restrict__ v_g, const float* __restrict__ kp,
    float* __restrict__ part)
{
  const int b = blockIdx.y, g = blockIdx.x;
  const int n = threadIdx.x & 63, mg = threadIdx.x >> 6;
  float acc[8] = {0,0,0,0,0,0,0,0};
  for (int tt = g*196; tt < (g+1)*196; ++tt){
    float vv = v_g[((size_t)b*TT + tt)*64 + n];
    const float4* kp4 = (const float4*)(kp + ((size_t)b*TT + tt)*MM + mg*8);
    float4 a0 = kp4[0], a1 = kp4[1];
    acc[0] += vv*a0.x; acc[1] += vv*a0.y; acc[2] += vv*a0.z; acc[3] += vv*a0.w;
    acc[4] += vv*a1.x; acc[5] += vv*a1.y; acc[6] += vv*a1.z; acc[7] += vv*a1.w;
  }
  #pragma unroll
  for (int j=0;j<8;++j)
    part[(((size_t)g*BB + b)*64 + n)*MM + mg*8 + j] = acc[j];
}

__global__ __launch_bounds__(256) void k_kptv_red(
    const float* __restrict__ part, float* __restrict__ kptv)
{
  const int idx = blockIdx.x*256 + threadIdx.x;
  float a = 0.f;
  #pragma unroll
  for (int g=0; g<16; ++g) a += part[(size_t)g*65536 + idx];
  kptv[idx] = a;
}

// ---------------- attention out + proj + residuals -> xo (d_out); 32 pos/block
__global__ __launch_bounds__(256) void k_attn(
    const float* __restrict__ v_g, const float* __restrict__ qp,
    const float* __restrict__ kpsum, const float* __restrict__ kptv,
    const float* __restrict__ projw, const float* __restrict__ projb,
    const float* __restrict__ convX, float* __restrict__ xo)
{
  __shared__ float pw[64*65];
  __shared__ float ktv[64*33];
  __shared__ float ks[32];
  __shared__ float tsh[4][64];
  const int t = threadIdx.x, n = t & 63, p = t >> 6;
  const int b = blockIdx.y;
  for (int idx=t; idx<4096; idx+=256) pw[(idx>>6)*65 + (idx&63)] = projw[idx];
  for (int idx=t; idx<2048; idx+=256) ktv[(idx>>5)*33 + (idx&31)] = kptv[b*2048 + idx];
  if (t < 32) ks[t] = kpsum[b*MM + t];
  __syncthreads();
  const float pb = projb[n];
  for (int sp=0; sp<8; ++sp){
    const int s = blockIdx.x*32 + sp*4 + p;
    const float* qpp = qp + ((size_t)b*TT + s)*MM;
    float D = 0.f, num = 0.f;
    #pragma unroll 8
    for (int m=0;m<32;++m){
      float q = qpp[m];
      D   += q*ks[m];
      num += q*ktv[n*33+m];
    }
    tsh[p][n] = num / (D + 1e-8f);
    __syncthreads();
    float acc = pb;
    #pragma unroll 8
    for (int j=0;j<64;++j) acc += tsh[p][j]*pw[n*65+j];
    const size_t off = ((size_t)b*TT + s)*64 + n;
    xo[off] = v_g[off] + acc + convX[off];
    __syncthreads();
  }
}

// ---------------- final MLP, in place on d_out; 32 pos/block
__global__ __launch_bounds__(256) void k_mlp(
    const float* __restrict__ ln2_g, const float* __restrict__ ln2_b,
    const float* __restrict__ w1, const float* __restrict__ b1,
    const float* __restrict__ w2, const float* __restrict__ b2,
    float* __restrict__ out)
{
  __shared__ float w1s[64*65], w2s[64*65];
  __shared__ float lnsh[4][64], h1sh[4][64];
  const int t = threadIdx.x, n = t & 63, p = t >> 6;
  const int b = blockIdx.y;
  for (int idx=t; idx<4096; idx+=256){
    int r = idx >> 6, c = idx & 63;
    w1s[r*65+c] = w1[idx];
    w2s[r*65+c] = w2[idx];
  }
  __syncthreads();
  const float g2 = ln2_g[n], bb2 = ln2_b[n];
  const float bb1 = b1[n], bbo = b2[n];
  for (int sp=0; sp<8; ++sp){
    const int s = blockIdx.x*32 + sp*4 + p;
    const size_t off = ((size_t)b*TT + s)*64;
    const float xv = out[off + n];
    float s1 = xv, s2 = xv*xv;
    #pragma unroll
    for (int o=32;o;o>>=1){
      s1 += __shfl_xor(s1, o, 64);
      s2 += __shfl_xor(s2, o, 64);
    }
    float mu = s1*(1.f/64.f);
    float rs = rsqrtf(s2*(1.f/64.f) - mu*mu + 1e-5f);
    lnsh[p][n] = (xv - mu)*rs*g2 + bb2;
    __syncthreads();
    float acc = bb1;
    #pragma unroll 8
    for (int c=0;c<64;++c) acc += lnsh[p][c]*w1s[n*65+c];
    h1sh[p][n] = geluf(acc);
    __syncthreads();
    float acc2 = bbo;
    #pragma unroll 8
    for (int c=0;c<64;++c) acc2 += h1sh[p][c]*w2s[n*65+c];
    out[off + n] = xv + acc2;
    __syncthreads();
  }
}

extern "C" void kernel_launch(void* const* d_in, const int* in_sizes, int n_in,
                              void* d_out, int out_size, void* d_ws, size_t ws_size,
                              hipStream_t stream)
{
  const float* x      = (const float*)d_in[0];
  const float* prm_w  = (const float*)d_in[1];
  const float* prm_b  = (const float*)d_in[2];
  const float* pcm_w1 = (const float*)d_in[3];
  const float* pcm_b1 = (const float*)d_in[4];
  const float* pcm_w2 = (const float*)d_in[5];
  const float* pcm_b2 = (const float*)d_in[6];
  const float* bn_g   = (const float*)d_in[7];
  const float* bn_b   = (const float*)d_in[8];
  const float* bn_mean= (const float*)d_in[9];
  const float* bn_var = (const float*)d_in[10];
  const float* pcm_w3 = (const float*)d_in[11];
  const float* pcm_b3 = (const float*)d_in[12];
  const float* ln1_g  = (const float*)d_in[13];
  const float* ln1_b  = (const float*)d_in[14];
  const float* kqv_w  = (const float*)d_in[15];
  const float* kqv_b  = (const float*)d_in[16];
  const float* w_perf = (const float*)d_in[17];
  const float* proj_w = (const float*)d_in[18];
  const float* proj_b = (const float*)d_in[19];
  const float* ln2_g  = (const float*)d_in[20];
  const float* ln2_b  = (const float*)d_in[21];
  const float* mlp_w1 = (const float*)d_in[22];
  const float* mlp_b1 = (const float*)d_in[23];
  const float* mlp_w2 = (const float*)d_in[24];
  const float* mlp_b2 = (const float*)d_in[25];

  float* ws = (float*)d_ws;
  float* convX = ws + OFF_CONVX;
  __hip_bfloat16* xn  = (__hip_bfloat16*)(ws + OFF_XN);
  __hip_bfloat16* c2b = (__hip_bfloat16*)(ws + OFF_C2B);
  __hip_bfloat16* c1b = (__hip_bfloat16*)(ws + OFF_C1B);
  float* v_g   = ws + OFF_V;
  float* kp    = ws + OFF_KP;
  float* qp    = ws + OFF_QP;
  float* part  = ws + OFF_PART;
  float* kptv  = ws + OFF_KPTV;
  float* kpsum = ws + OFF_KPSUM;
  float* wpt   = ws + OFF_WPT;
  __hip_bfloat16* wkb  = (__hip_bfloat16*)(ws + OFF_WKB);
  __hip_bfloat16* wc2b = (__hip_bfloat16*)(ws + OFF_WC2B);
  __hip_bfloat16* wt3b = (__hip_bfloat16*)(ws + OFF_WT3B);
  float* out   = (float*)d_out;

  k_wtrans<<<dim3(627), 256, 0, stream>>>(prm_w, kqv_w, pcm_w2, pcm_w3,
                                          wpt, wkb, wc2b, wt3b);
  // CNN stem
  k_conv1<<<dim3(56,BB), 256, 0, stream>>>(x, pcm_w1, pcm_b1, c1b);
  k_conv2<<<dim3(49,BB), 256, 0, stream>>>(c1b, wc2b, pcm_b2, bn_g, bn_b,
                                           bn_mean, bn_var, c2b);
  k_conv3<<<dim3(49,BB), 256, 0, stream>>>(c2b, wt3b, pcm_b3, convX);
  // PRM + LN -> xn (bf16)
  k_prm_ln<<<dim3(224,BB), 256, 0, stream>>>(x, wpt, prm_b, ln1_g, ln1_b, xn);
  // KQV GEMM (MFMA) + Performer features
  k_kqv_perf<<<dim3(1568), 256, 0, stream>>>(xn, wkb, kqv_b, w_perf, v_g, kp, qp);
  // Performer reductions
  k_kpsum<<<dim3(BB), 256, 0, stream>>>(kp, kpsum);
  k_kptv<<<dim3(16,BB), 256, 0, stream>>>(v_g, kp, part);
  k_kptv_red<<<dim3(256), 256, 0, stream>>>(part, kptv);
  // attention output + residuals -> xo in d_out
  k_attn<<<dim3(98,BB), 256, 0, stream>>>(v_g, qp, kpsum, kptv, proj_w, proj_b,
                                          convX, out);
  // final MLP in place
  k_mlp<<<dim3(98,BB), 256, 0, stream>>>(ln2_g, ln2_b, mlp_w1, mlp_b1,
                                         mlp_w2, mlp_b2, out);
}

// Round 9
// 950.537 us; speedup vs baseline: 1.3529x; 1.3529x over previous
//
#include <hip/hip_runtime.h>
#include <hip/hip_bf16.h>
#include <cstddef>

// Problem constants
#define BB    32
#define IMG   224
#define CIN   3
#define ED    64
#define TD    64
#define MM    32
#define HP    56
#define TT    3136      // 56*56
#define C4    256       // 4*ED
#define KQVN  192       // 3*TD

typedef __attribute__((ext_vector_type(8))) short bf16x8;
typedef __attribute__((ext_vector_type(4))) float f32x4;

// workspace offsets (float units). Temporal plan:
//  step1 wtrans -> weights (aliased in PART region, dead after kqv)
//  step2 conv1 -> c1b  [19.27M,32.11M)
//  step3 conv2 -> c2b  [6.42M,9.63M)      (reads c1b)
//  step4 conv3 -> convX[0,6.42M)          (reads c2b)
//  step5 prm_ln -> xn  [6.42M,19.27M)     (c2b dead; xn overwrites c2b zone)
//  step6 kqv   -> v[19.27M,25.69M) kp[25.69M,28.9M) qp[28.9M,32.11M)  (c1b dead)
//  step7+ kptv -> part[32.11M,33.16M) (weights dead, overwritten)
#define OFF_CONVX  0u           // 6,422,528 f
#define OFF_XN     6422528u     // 12,845,056 f (25,690,112 bf16)
#define OFF_C2B    6422528u     // 3,211,264 f (bf16) — aliases xn head; dead before xn written
#define OFF_C1B    19267584u    // 12,845,056 f (bf16) — dead before v/kp/qp written
#define OFF_V      19267584u    // 6,422,528 f
#define OFF_KP     25690112u    // 3,211,264 f
#define OFF_QP     28901376u    // 3,211,264 f
#define OFF_PART   32112640u    // 1,048,576 f
#define OFF_KPTV   33161216u    // 65,536 f
#define OFF_KPSUM  33226752u    // 1,024 f
// weights aliased into PART region (dead once k_kptv writes part)
#define OFF_WPT    (OFF_PART)             // 37,632 f
#define OFF_WKB    (OFF_PART + 37632u)    // 24,576 f (49,152 bf16)
#define OFF_WC2B   (OFF_PART + 62208u)    // 18,432 f (36,864 bf16)
#define OFF_WT3B   (OFF_PART + 80640u)    // 18,432 f (36,864 bf16)  ends OFF_PART+99,072
// total 33,227,776 f = 132.9 MB

__device__ __forceinline__ float geluf(float v){
  return 0.5f*v*(1.f + erff(v*0.70710678118654752f));
}
__device__ __forceinline__ float siluf(float v){
  return v/(1.f + expf(-v));
}
__device__ __forceinline__ ushort bfbits(float v){
  __hip_bfloat16 h = __float2bfloat16(v);
  return *reinterpret_cast<ushort*>(&h);
}

// ---------------- weight transposes / casts
__global__ __launch_bounds__(256) void k_wtrans(
    const float* __restrict__ prm_w, const float* __restrict__ kqv_w,
    const float* __restrict__ pcm_w2, const float* __restrict__ pcm_w3,
    float* __restrict__ wpt, __hip_bfloat16* __restrict__ wkb,
    __hip_bfloat16* __restrict__ wc2b, __hip_bfloat16* __restrict__ wt3b)
{
  int idx = blockIdx.x*256 + threadIdx.x;
  if (idx < 37632){
    int oc = idx & 63, r = idx >> 6;        // r = i*147+tap
    int i = r/147, tap = r - i*147;
    wpt[idx] = prm_w[(i*64 + oc)*147 + tap];
  } else if (idx < 86784){
    int i4 = idx - 37632;                   // [j][c] row-major straight cast
    wkb[i4] = __float2bfloat16(kqv_w[i4]);
  } else if (idx < 123648){
    int i2 = idx - 86784;                   // wc2b[oc][ (kh*3+kw)*64+ci ]
    int oc = i2/576, rem = i2 - oc*576;
    int khkw = rem >> 6, ci = rem & 63;
    int kh = khkw/3, kw = khkw - kh*3;
    wc2b[i2] = __float2bfloat16(pcm_w2[(oc*64+ci)*9 + kh*3 + kw]);
  } else if (idx < 160512){
    int i3 = idx - 123648;
    int oc = i3/576, rem = i3 - oc*576;
    int khkw = rem >> 6, ci = rem & 63;
    int kh = khkw/3, kw = khkw - kh*3;
    wt3b[i3] = __float2bfloat16(pcm_w3[(oc*64+ci)*9 + kh*3 + kw]);
  }
}

// ---------------- conv1: x(32,3,224,224) -> c1b NHWC bf16 (32,112,112,64), 3x3 s2 p1, SiLU
__global__ __launch_bounds__(256) void k_conv1(
    const float* __restrict__ x, const float* __restrict__ w,
    const float* __restrict__ bias, __hip_bfloat16* __restrict__ c1b)
{
  __shared__ __align__(16) float xs[3][5][226];
  __shared__ float ws1[1728];
  __shared__ float bs[64];
  const int t = threadIdx.x;
  const int b = blockIdx.y;
  const int oh0 = blockIdx.x*2;
  const int ih0 = oh0*2 - 1;
  const float* xb = x + (size_t)b*CIN*IMG*IMG;
  for (int idx = t; idx < 3390; idx += 256){
    int ci = idx/1130, rem = idx - ci*1130;
    int r = rem/226, c = rem - r*226;
    int ih = ih0 + r, iw = c - 1;
    float v = 0.f;
    if ((unsigned)ih < (unsigned)IMG && (unsigned)iw < (unsigned)IMG)
      v = xb[(ci*IMG+ih)*IMG+iw];
    xs[ci][r][c] = v;
  }
  for (int idx = t; idx < 1728; idx += 256) ws1[idx] = w[idx];
  if (t < 64) bs[t] = bias[t];
  __syncthreads();
  if (t < 224){
    const int orow = t/112, ow = t - orow*112;
    const int rb = orow*2, cb = ow*2;
    float xr[3][3][3];
    #pragma unroll
    for (int ci=0;ci<3;++ci)
      #pragma unroll
      for (int kh=0;kh<3;++kh)
        #pragma unroll
        for (int kw=0;kw<3;++kw)
          xr[ci][kh][kw] = xs[ci][rb+kh][cb+kw];
    const int oh = oh0 + orow;
    __hip_bfloat16* dst = c1b + (((size_t)b*112+oh)*112+ow)*64;
    for (int og=0; og<8; ++og){
      ushort h8[8];
      #pragma unroll
      for (int u=0;u<8;++u){
        const int oc = og*8+u;
        float acc = bs[oc];
        const float* wp = &ws1[oc*27];
        #pragma unroll
        for (int ci=0;ci<3;++ci)
          #pragma unroll
          for (int kh=0;kh<3;++kh)
            #pragma unroll
            for (int kw=0;kw<3;++kw)
              acc += wp[(ci*3+kh)*3+kw]*xr[ci][kh][kw];
        h8[u] = bfbits(siluf(acc));
      }
      *(uint4*)(dst + og*8) = *(const uint4*)h8;
    }
  }
}

// ---------------- conv2 (MFMA implicit GEMM): c1b -> c2b NHWC bf16, 3x3 s2 p1, BN+SiLU
__global__ __launch_bounds__(256) void k_conv2(
    const __hip_bfloat16* __restrict__ c1b, const __hip_bfloat16* __restrict__ wc2b,
    const float* __restrict__ bias, const float* __restrict__ g,
    const float* __restrict__ bb, const float* __restrict__ mean,
    const float* __restrict__ var, __hip_bfloat16* __restrict__ c2b)
{
  __shared__ __align__(16) ushort xs[17*17*72];
  const int b = blockIdx.y;
  const int th = blockIdx.x/7, tw = blockIdx.x - th*7;
  const int oh0 = th*8, ow0 = tw*8;
  const int t = threadIdx.x;
  const int w = t>>6, lane = t&63, l15 = lane&15, hi = lane>>4;

  const int ih0 = oh0*2-1, iw0 = ow0*2-1;
  const ushort* c1u = (const ushort*)c1b;
  for (int seg = t; seg < 2312; seg += 256){
    int pos = seg >> 3, s8 = seg & 7;
    int r = pos/17, c = pos - r*17;
    int ih = ih0 + r, iw = iw0 + c;
    uint4 val = {0,0,0,0};
    if ((unsigned)ih < 112u && (unsigned)iw < 112u)
      val = *(const uint4*)&c1u[(((size_t)b*112+ih)*112+iw)*64 + s8*8];
    *(uint4*)&xs[(r*17+c)*72 + s8*8] = val;
  }
  __syncthreads();

  float bs4[4], iv4[4], mn4[4], bo4[4];
  #pragma unroll
  for (int nb=0;nb<4;++nb){
    int oc = nb*16+l15;
    bs4[nb] = bias[oc];
    iv4[nb] = g[oc]*rsqrtf(var[oc]+1e-5f);
    mn4[nb] = mean[oc];
    bo4[nb] = bb[oc];
  }

  f32x4 acc[4];
  #pragma unroll
  for (int nb=0;nb<4;++nb) acc[nb] = (f32x4){0.f,0.f,0.f,0.f};

  const int p = w*16 + l15, pr = p>>3, pc = p&7;
  const ushort* wq = (const ushort*)wc2b;

  for (int ks=0; ks<18; ++ks){
    const int k0 = ks*32 + hi*8;
    const int khkw = k0 >> 6, ci0 = k0 & 63;
    const int kh = khkw/3, kw = khkw - kh*3;
    bf16x8 a = *(const bf16x8*)&xs[((2*pr+kh)*17 + 2*pc+kw)*72 + ci0];
    #pragma unroll
    for (int nb=0;nb<4;++nb){
      bf16x8 bv = *(const bf16x8*)&wq[(nb*16+l15)*576 + k0];
      acc[nb] = __builtin_amdgcn_mfma_f32_16x16x32_bf16(a, bv, acc[nb], 0, 0, 0);
    }
  }

  #pragma unroll
  for (int nb=0;nb<4;++nb){
    #pragma unroll
    for (int r=0;r<4;++r){
      int pp = w*16 + hi*4 + r;
      int oh = oh0 + (pp>>3), ow = ow0 + (pp&7);
      float vv = acc[nb][r] + bs4[nb];
      vv = (vv - mn4[nb])*iv4[nb] + bo4[nb];
      c2b[(((size_t)b*56+oh)*56+ow)*64 + nb*16+l15] = __float2bfloat16(siluf(vv));
    }
  }
}

// ---------------- conv3 (MFMA implicit GEMM): c2b -> convX(32,3136,64) f32 NHWC, 3x3 s1 p1, SiLU
__global__ __launch_bounds__(256) void k_conv3(
    const __hip_bfloat16* __restrict__ c2b, const __hip_bfloat16* __restrict__ wt3b,
    const float* __restrict__ bias, float* __restrict__ convX)
{
  __shared__ __align__(16) ushort xs[10*12*72];
  const int b = blockIdx.y;
  const int th = blockIdx.x/7, tw = blockIdx.x - th*7;
  const int oh0 = th*8, ow0 = tw*8;
  const int t = threadIdx.x;
  const int w = t>>6, lane = t&63, l15 = lane&15, hi = lane>>4;

  const ushort* c2u = (const ushort*)c2b;
  for (int seg = t; seg < 960; seg += 256){
    int pos = seg >> 3, s8 = seg & 7;
    int r = pos/12, c = pos - r*12;
    int ih = oh0 - 1 + r, iw = ow0 - 1 + c;
    uint4 val = {0,0,0,0};
    if ((unsigned)ih < 56u && (unsigned)iw < 56u)
      val = *(const uint4*)&c2u[(((size_t)b*56+ih)*56+iw)*64 + s8*8];
    *(uint4*)&xs[(r*12+c)*72 + s8*8] = val;
  }
  __syncthreads();

  float bs4[4];
  #pragma unroll
  for (int nb=0;nb<4;++nb) bs4[nb] = bias[nb*16+l15];

  f32x4 acc[4];
  #pragma unroll
  for (int nb=0;nb<4;++nb) acc[nb] = (f32x4){0.f,0.f,0.f,0.f};

  const int p = w*16 + l15, pr = p>>3, pc = p&7;
  const ushort* wq = (const ushort*)wt3b;

  for (int ks=0; ks<18; ++ks){
    const int k0 = ks*32 + hi*8;
    const int khkw = k0 >> 6, ci0 = k0 & 63;
    const int kh = khkw/3, kw = khkw - kh*3;
    bf16x8 a = *(const bf16x8*)&xs[((pr+kh)*12 + pc+kw)*72 + ci0];
    #pragma unroll
    for (int nb=0;nb<4;++nb){
      bf16x8 bv = *(const bf16x8*)&wq[(nb*16+l15)*576 + k0];
      acc[nb] = __builtin_amdgcn_mfma_f32_16x16x32_bf16(a, bv, acc[nb], 0, 0, 0);
    }
  }

  #pragma unroll
  for (int nb=0;nb<4;++nb){
    #pragma unroll
    for (int r=0;r<4;++r){
      int pp = w*16 + hi*4 + r;
      int oh = oh0 + (pp>>3), ow = ow0 + (pp&7);
      int s = oh*HP + ow;
      convX[((size_t)b*TT + s)*64 + nb*16+l15] = siluf(acc[nb][r] + bs4[nb]);
    }
  }
}

// ---------------- PRM convs + GELU + LN -> xn (bf16). one block = 14-wide strip
// R3-verified VALU version (fp32 math; passed absmax 0.0195 @ 323 us).
__global__ __launch_bounds__(256) void k_prm_ln(
    const float* __restrict__ x, const float* __restrict__ wpt,
    const float* __restrict__ prm_b, const float* __restrict__ ln_g,
    const float* __restrict__ ln_b, __hip_bfloat16* __restrict__ xn)
{
  __shared__ __align__(16) float xt[3][25][80];
  __shared__ float wred[4][14][2];
  const int t = threadIdx.x;
  const int b = blockIdx.y;
  const int oh  = blockIdx.x >> 2;
  const int owt = blockIdx.x & 3;
  const int ow0 = owt*14;
  const int ih0 = oh*4 - 11;
  const int iw0 = ow0*4 - 11;

  const float* xb = x + (size_t)b*CIN*IMG*IMG;
  for (int idx = t; idx < 6000; idx += 256){
    int ci  = idx / 2000;
    int rem = idx - ci*2000;
    int r   = rem / 80;
    int cc  = rem - r*80;
    int ih = ih0 + r, iw = iw0 + cc;
    float val = 0.f;
    if ((unsigned)ih < (unsigned)IMG && (unsigned)iw < (unsigned)IMG)
      val = xb[(ci*IMG+ih)*IMG+iw];
    xt[ci][r][cc] = val;
  }
  __syncthreads();

  const int i = t >> 6, lane = t & 63;
  const int d = i + 1;
  const int r0 = 12 - 3*d;
  float v[14];
  const float bi = prm_b[i*64+lane];
  #pragma unroll
  for (int p=0;p<14;++p) v[p] = bi;
  const float* wq = wpt + (i*147)*64 + lane;   // [tap][oc] coalesced/broadcast

  for (int ci=0; ci<3; ++ci){
    for (int kh=0; kh<7; ++kh){
      const int rh = r0 + kh*d;
      const float* xrow = &xt[ci][rh][0];
      #pragma unroll
      for (int kw=0; kw<7; ++kw){
        const float wv = wq[((ci*7+kh)*7+kw)*64];
        const int rw = r0 + kw*d;
        #pragma unroll
        for (int p=0;p<14;++p)
          v[p] += wv * xrow[p*4 + rw];
      }
    }
  }
  // GELU + per-wave LN partials via shuffles
  #pragma unroll
  for (int p=0;p<14;++p) v[p] = geluf(v[p]);
  #pragma unroll
  for (int p=0;p<14;++p){
    float s1 = v[p], s2 = v[p]*v[p];
    #pragma unroll
    for (int o=32;o;o>>=1){
      s1 += __shfl_xor(s1, o, 64);
      s2 += __shfl_xor(s2, o, 64);
    }
    if (lane == 0){ wred[i][p][0] = s1; wred[i][p][1] = s2; }
  }
  __syncthreads();
  const float lg = ln_g[t], lb = ln_b[t];
  const int s_base = oh*HP + ow0;
  #pragma unroll
  for (int p=0;p<14;++p){
    float S1 = wred[0][p][0]+wred[1][p][0]+wred[2][p][0]+wred[3][p][0];
    float S2 = wred[0][p][1]+wred[1][p][1]+wred[2][p][1]+wred[3][p][1];
    float mu = S1*(1.f/256.f);
    float rs = rsqrtf(S2*(1.f/256.f) - mu*mu + 1e-5f);
    float outv = (v[p]-mu)*rs*lg + lb;
    xn[((size_t)(b*TT + s_base + p))*256 + t] = __float2bfloat16(outv);
  }
}

// ---------------- KQV GEMM (bf16 MFMA) + fused Performer feature map
__global__ __launch_bounds__(256) void k_kqv_perf(
    const __hip_bfloat16* __restrict__ xn, const __hip_bfloat16* __restrict__ wkb,
    const float* __restrict__ kqv_b, const float* __restrict__ wperf,
    float* __restrict__ v_g, float* __restrict__ kp, float* __restrict__ qp)
{
  __shared__ __align__(16) char smem[36864];     // As[64][72] | Bs[192][72] bf16 ; reused as zq[64][129] f32
  __shared__ float wperf_s[32*65];
  __shared__ float kqvb_s[192];
  __shared__ float xd_s[128];
  ushort* As = (ushort*)smem;
  ushort* Bs = (ushort*)(smem + 9216);
  float*  zq = (float*)smem;

  const int t = threadIdx.x;
  const int m0 = blockIdx.x*64;
  const int w = t >> 6, lane = t & 63;
  const int l15 = lane & 15, hi = lane >> 4;

  for (int idx = t; idx < 2048; idx += 256)
    wperf_s[(idx>>6)*65 + (idx&63)] = wperf[idx];
  if (t < 192) kqvb_s[t] = kqv_b[t];

  f32x4 acc[12];
  #pragma unroll
  for (int nb=0;nb<12;++nb) acc[nb] = (f32x4){0.f,0.f,0.f,0.f};

  const ushort* xnu = (const ushort*)xn;
  const ushort* wku = (const ushort*)wkb;

  for (int kc=0; kc<4; ++kc){
    #pragma unroll
    for (int ss=0; ss<2; ++ss){
      int seg = ss*256 + t;
      int row = seg >> 3, c8 = seg & 7;
      *(uint4*)&As[row*72 + c8*8] =
        *(const uint4*)&xnu[((size_t)(m0+row))*256 + kc*64 + c8*8];
    }
    #pragma unroll
    for (int ss=0; ss<6; ++ss){
      int seg = ss*256 + t;
      int row = seg >> 3, c8 = seg & 7;
      *(uint4*)&Bs[row*72 + c8*8] =
        *(const uint4*)&wku[row*256 + kc*64 + c8*8];
    }
    __syncthreads();
    #pragma unroll
    for (int ks=0; ks<2; ++ks){
      bf16x8 a = *(const bf16x8*)&As[(16*w + l15)*72 + ks*32 + hi*8];
      #pragma unroll
      for (int nb=0;nb<12;++nb){
        bf16x8 bv = *(const bf16x8*)&Bs[(nb*16 + l15)*72 + ks*32 + hi*8];
        acc[nb] = __builtin_amdgcn_mfma_f32_16x16x32_bf16(a, bv, acc[nb], 0, 0, 0);
      }
    }
    __syncthreads();
  }

  #pragma unroll
  for (int nb=0;nb<12;++nb){
    int col = nb*16 + l15;
    float bias = kqvb_s[col];
    #pragma unroll
    for (int r=0;r<4;++r){
      int row = w*16 + hi*4 + r;
      float val = acc[nb][r] + bias;
      if (col < 128) zq[row*129 + col] = val;
      else v_g[((size_t)(m0+row))*64 + (col-128)] = val;
    }
  }
  __syncthreads();

  if (t < 128){
    int pos = t & 63, wh = t >> 6;
    float s = 0.f;
    #pragma unroll 8
    for (int c=0;c<64;++c){
      float z = zq[pos*129 + wh*64 + c];
      s += z*z;
    }
    xd_s[t] = 0.5f*s;
  }
  __syncthreads();

  const int m = t & 31;
  #pragma unroll
  for (int it=0; it<16; ++it){
    int qi = it*8 + (t>>5);
    int pos = qi & 63, wh = qi >> 6;
    const float* zr = &zq[pos*129 + wh*64];
    const float* wr = &wperf_s[m*65];
    float wtx = 0.f;
    #pragma unroll 8
    for (int c=0;c<64;++c) wtx += zr[c]*wr[c];
    float outv = expf(wtx - xd_s[qi]) * 0.17677669529663687f;
    float* dst = wh ? qp : kp;
    dst[((size_t)(m0+pos))*32 + m] = outv;
  }
}

// ---------------- kpsum[b][m] = sum_t kp[b][t][m]
__global__ __launch_bounds__(256) void k_kpsum(
    const float* __restrict__ kp, float* __restrict__ kpsum)
{
  const int b = blockIdx.x;
  const int m = threadIdx.x & 31, g = threadIdx.x >> 5;
  __shared__ float part[8][32];
  float s = 0.f;
  for (int tt = g; tt < TT; tt += 8)
    s += kp[((size_t)b*TT + tt)*MM + m];
  part[g][m] = s;
  __syncthreads();
  if (threadIdx.x < 32){
    float a = 0.f;
    #pragma unroll
    for (int g2=0;g2<8;++g2) a += part[g2][threadIdx.x];
    kpsum[b*MM + threadIdx.x] = a;
  }
}

// ---------------- kptv partials
__global__ __launch_bounds__(256) void k_kptv(
    const float* __restrict__ v_g, const float* __restrict__ kp,
    float* __restrict__ part)
{
  const int b = blockIdx.y, g = blockIdx.x;
  const int n = threadIdx.x & 63, mg = threadIdx.x >> 6;
  float acc[8] = {0,0,0,0,0,0,0,0};
  for (int tt = g*196; tt < (g+1)*196; ++tt){
    float vv = v_g[((size_t)b*TT + tt)*64 + n];
    const float4* kp4 = (const float4*)(kp + ((size_t)b*TT + tt)*MM + mg*8);
    float4 a0 = kp4[0], a1 = kp4[1];
    acc[0] += vv*a0.x; acc[1] += vv*a0.y; acc[2] += vv*a0.z; acc[3] += vv*a0.w;
    acc[4] += vv*a1.x; acc[5] += vv*a1.y; acc[6] += vv*a1.z; acc[7] += vv*a1.w;
  }
  #pragma unroll
  for (int j=0;j<8;++j)
    part[(((size_t)g*BB + b)*64 + n)*MM + mg*8 + j] = acc[j];
}

__global__ __launch_bounds__(256) void k_kptv_red(
    const float* __restrict__ part, float* __restrict__ kptv)
{
  const int idx = blockIdx.x*256 + threadIdx.x;
  float a = 0.f;
  #pragma unroll
  for (int g=0; g<16; ++g) a += part[(size_t)g*65536 + idx];
  kptv[idx] = a;
}

// ---------------- attention out + proj + residuals -> xo (d_out); 32 pos/block
__global__ __launch_bounds__(256) void k_attn(
    const float* __restrict__ v_g, const float* __restrict__ qp,
    const float* __restrict__ kpsum, const float* __restrict__ kptv,
    const float* __restrict__ projw, const float* __restrict__ projb,
    const float* __restrict__ convX, float* __restrict__ xo)
{
  __shared__ float pw[64*65];
  __shared__ float ktv[64*33];
  __shared__ float ks[32];
  __shared__ float tsh[4][64];
  const int t = threadIdx.x, n = t & 63, p = t >> 6;
  const int b = blockIdx.y;
  for (int idx=t; idx<4096; idx+=256) pw[(idx>>6)*65 + (idx&63)] = projw[idx];
  for (int idx=t; idx<2048; idx+=256) ktv[(idx>>5)*33 + (idx&31)] = kptv[b*2048 + idx];
  if (t < 32) ks[t] = kpsum[b*MM + t];
  __syncthreads();
  const float pb = projb[n];
  for (int sp=0; sp<8; ++sp){
    const int s = blockIdx.x*32 + sp*4 + p;
    const float* qpp = qp + ((size_t)b*TT + s)*MM;
    float D = 0.f, num = 0.f;
    #pragma unroll 8
    for (int m=0;m<32;++m){
      float q = qpp[m];
      D   += q*ks[m];
      num += q*ktv[n*33+m];
    }
    tsh[p][n] = num / (D + 1e-8f);
    __syncthreads();
    float acc = pb;
    #pragma unroll 8
    for (int j=0;j<64;++j) acc += tsh[p][j]*pw[n*65+j];
    const size_t off = ((size_t)b*TT + s)*64 + n;
    xo[off] = v_g[off] + acc + convX[off];
    __syncthreads();
  }
}

// ---------------- final MLP, in place on d_out; 32 pos/block
__global__ __launch_bounds__(256) void k_mlp(
    const float* __restrict__ ln2_g, const float* __restrict__ ln2_b,
    const float* __restrict__ w1, const float* __restrict__ b1,
    const float* __restrict__ w2, const float* __restrict__ b2,
    float* __restrict__ out)
{
  __shared__ float w1s[64*65], w2s[64*65];
  __shared__ float lnsh[4][64], h1sh[4][64];
  const int t = threadIdx.x, n = t & 63, p = t >> 6;
  const int b = blockIdx.y;
  for (int idx=t; idx<4096; idx+=256){
    int r = idx >> 6, c = idx & 63;
    w1s[r*65+c] = w1[idx];
    w2s[r*65+c] = w2[idx];
  }
  __syncthreads();
  const float g2 = ln2_g[n], bb2 = ln2_b[n];
  const float bb1 = b1[n], bbo = b2[n];
  for (int sp=0; sp<8; ++sp){
    const int s = blockIdx.x*32 + sp*4 + p;
    const size_t off = ((size_t)b*TT + s)*64;
    const float xv = out[off + n];
    float s1 = xv, s2 = xv*xv;
    #pragma unroll
    for (int o=32;o;o>>=1){
      s1 += __shfl_xor(s1, o, 64);
      s2 += __shfl_xor(s2, o, 64);
    }
    float mu = s1*(1.f/64.f);
    float rs = rsqrtf(s2*(1.f/64.f) - mu*mu + 1e-5f);
    lnsh[p][n] = (xv - mu)*rs*g2 + bb2;
    __syncthreads();
    float acc = bb1;
    #pragma unroll 8
    for (int c=0;c<64;++c) acc += lnsh[p][c]*w1s[n*65+c];
    h1sh[p][n] = geluf(acc);
    __syncthreads();
    float acc2 = bbo;
    #pragma unroll 8
    for (int c=0;c<64;++c) acc2 += h1sh[p][c]*w2s[n*65+c];
    out[off + n] = xv + acc2;
    __syncthreads();
  }
}

extern "C" void kernel_launch(void* const* d_in, const int* in_sizes, int n_in,
                              void* d_out, int out_size, void* d_ws, size_t ws_size,
                              hipStream_t stream)
{
  const float* x      = (const float*)d_in[0];
  const float* prm_w  = (const float*)d_in[1];
  const float* prm_b  = (const float*)d_in[2];
  const float* pcm_w1 = (const float*)d_in[3];
  const float* pcm_b1 = (const float*)d_in[4];
  const float* pcm_w2 = (const float*)d_in[5];
  const float* pcm_b2 = (const float*)d_in[6];
  const float* bn_g   = (const float*)d_in[7];
  const float* bn_b   = (const float*)d_in[8];
  const float* bn_mean= (const float*)d_in[9];
  const float* bn_var = (const float*)d_in[10];
  const float* pcm_w3 = (const float*)d_in[11];
  const float* pcm_b3 = (const float*)d_in[12];
  const float* ln1_g  = (const float*)d_in[13];
  const float* ln1_b  = (const float*)d_in[14];
  const float* kqv_w  = (const float*)d_in[15];
  const float* kqv_b  = (const float*)d_in[16];
  const float* w_perf = (const float*)d_in[17];
  const float* proj_w = (const float*)d_in[18];
  const float* proj_b = (const float*)d_in[19];
  const float* ln2_g  = (const float*)d_in[20];
  const float* ln2_b  = (const float*)d_in[21];
  const float* mlp_w1 = (const float*)d_in[22];
  const float* mlp_b1 = (const float*)d_in[23];
  const float* mlp_w2 = (const float*)d_in[24];
  const float* mlp_b2 = (const float*)d_in[25];

  float* ws = (float*)d_ws;
  float* convX = ws + OFF_CONVX;
  __hip_bfloat16* xn  = (__hip_bfloat16*)(ws + OFF_XN);
  __hip_bfloat16* c2b = (__hip_bfloat16*)(ws + OFF_C2B);
  __hip_bfloat16* c1b = (__hip_bfloat16*)(ws + OFF_C1B);
  float* v_g   = ws + OFF_V;
  float* kp    = ws + OFF_KP;
  float* qp    = ws + OFF_QP;
  float* part  = ws + OFF_PART;
  float* kptv  = ws + OFF_KPTV;
  float* kpsum = ws + OFF_KPSUM;
  float* wpt   = ws + OFF_WPT;
  __hip_bfloat16* wkb  = (__hip_bfloat16*)(ws + OFF_WKB);
  __hip_bfloat16* wc2b = (__hip_bfloat16*)(ws + OFF_WC2B);
  __hip_bfloat16* wt3b = (__hip_bfloat16*)(ws + OFF_WT3B);
  float* out   = (float*)d_out;

  k_wtrans<<<dim3(627), 256, 0, stream>>>(prm_w, kqv_w, pcm_w2, pcm_w3,
                                          wpt, wkb, wc2b, wt3b);
  // CNN stem
  k_conv1<<<dim3(56,BB), 256, 0, stream>>>(x, pcm_w1, pcm_b1, c1b);
  k_conv2<<<dim3(49,BB), 256, 0, stream>>>(c1b, wc2b, pcm_b2, bn_g, bn_b,
                                           bn_mean, bn_var, c2b);
  k_conv3<<<dim3(49,BB), 256, 0, stream>>>(c2b, wt3b, pcm_b3, convX);
  // PRM + LN -> xn (bf16)
  k_prm_ln<<<dim3(224,BB), 256, 0, stream>>>(x, wpt, prm_b, ln1_g, ln1_b, xn);
  // KQV GEMM (MFMA) + Performer features
  k_kqv_perf<<<dim3(1568), 256, 0, stream>>>(xn, wkb, kqv_b, w_perf, v_g, kp, qp);
  // Performer reductions
  k_kpsum<<<dim3(BB), 256, 0, stream>>>(kp, kpsum);
  k_kptv<<<dim3(16,BB), 256, 0, stream>>>(v_g, kp, part);
  k_kptv_red<<<dim3(256), 256, 0, stream>>>(part, kptv);
  // attention output + residuals -> xo in d_out
  k_attn<<<dim3(98,BB), 256, 0, stream>>>(v_g, qp, kpsum, kptv, proj_w, proj_b,
                                          convX, out);
  // final MLP in place
  k_mlp<<<dim3(98,BB), 256, 0, stream>>>(ln2_g, ln2_b, mlp_w1, mlp_b1,
                                         mlp_w2, mlp_b2, out);
}